// Round 4
// baseline (648.572 us; speedup 1.0000x reference)
//
#include <hip/hip_runtime.h>
#include <math.h>

// RealNVP, 8 layers, B=262144, H=128, scalar coupling input.
// Full piecewise-linear collapse: within breakpoint-interval k of x,
// st_pre(x) is PWL; per interval we build sorted relu crossings + segment
// records in POINT-SLOPE form st(x) = V + A*(x - ref), ref inside the
// segment and V computed as a direct per-unit relu-sum. BN stats exact from
// per-interval moments. Table math in double (tiny kernels).
// R3 bug fixed here: k_hist binary search ran 7 fixed iters over a
// 129-value answer space (and read lts[128] OOB) -> off-by-one bins ->
// O(1) extrapolation errors. Now a proper lower_bound while-loop.

#define BN_ 262144
#define H_ 128
#define NBINS 129

// ws layout (float offsets)
#define OFF_ST  (3*BN_)                    // 4: stats[par]={sum,sumsq}
#define OFF_BIN (3*BN_+8)                  // 512: cnt[0..131], sx[+132], sxx[+264]
#define OFF_TS  (3*BN_+520)                // 128: sorted breakpoints
#define OFF_S   (3*BN_+648)                // float2 S[k][i], k-major: 129*128
#define OFF_XS  (OFF_S + 2*NBINS*H_)       // crossings: 129 rows stride 132
#define OFF_SEG (OFF_XS + NBINS*132)       // float4 seg[k][r]=(A_s,V_s,A_t,V_t)
#define OFF_REF (OFF_SEG + NBINS*132*4)    // float ref[k][r], stride 132
#define OFF_CNT (OFF_REF + NBINS*132)      // 129 ints
#define OFF_BB  (OFF_CNT + 132)            // uchar[B]

__global__ void k_zero(float* ws) {
    if (threadIdx.x < 4) ws[OFF_ST + threadIdx.x] = 0.f;
}

__global__ __launch_bounds__(1024) void k_init(const float* __restrict__ x,
                                               float* __restrict__ ws) {
    int b = blockIdx.x * 1024 + threadIdx.x;
    float2 xv = ((const float2*)x)[b];
    ws[b] = xv.x;
    ws[BN_ + b] = xv.y;
    ws[2*BN_ + b] = 0.f;
    float s = xv.y, ss = xv.y * xv.y;
    for (int off = 32; off; off >>= 1) {
        s += __shfl_down(s, off);
        ss += __shfl_down(ss, off);
    }
    __shared__ float rs[16], rss[16];
    int lane = threadIdx.x & 63, wid = threadIdx.x >> 6;
    if (lane == 0) { rs[wid] = s; rss[wid] = ss; }
    __syncthreads();
    if (threadIdx.x == 0) {
        float a = 0.f, c = 0.f;
        for (int w = 0; w < 16; w++) { a += rs[w]; c += rss[w]; }
        atomicAdd(&ws[OFF_ST + 0], a);
        atomicAdd(&ws[OFF_ST + 1], c);
    }
}

__device__ __forceinline__ double bredd(double v, volatile double* tmp, int tid) {
    for (int off = 32; off; off >>= 1) v += __shfl_down(v, off);
    if ((tid & 63) == 0) tmp[tid >> 6] = v;
    __syncthreads();
    double r = tmp[0] + tmp[1];
    __syncthreads();
    return r;
}

// 128 blocks x 128: block i builds S-table column i (k-major rows) in double,
// block 0 writes SORTED breakpoints, zeroes bins + next stats slot.
__global__ __launch_bounds__(128) void k_prep(
    const float* __restrict__ v1, const float* __restrict__ g1,
    const float* __restrict__ bn1g, const float* __restrict__ bn1b,
    const float* __restrict__ v2, const float* __restrict__ g2,
    const float* __restrict__ b2,
    float* __restrict__ ws, int l, int par) {
    const int j = threadIdx.x, i = blockIdx.x;
    __shared__ float sA[H_], sC[H_], sT[H_], vrow[H_];
    __shared__ int order[H_];
    __shared__ double2 scan2[H_];
    __shared__ double redd[2];

    double Ssum = ws[OFF_ST + 2*par], SSq = ws[OFF_ST + 2*par + 1];
    double mx = Ssum * (1.0 / BN_);
    double vx = fmax(SSq * (1.0 / BN_) - mx * mx, 0.0);

    // BN1 folded: h1_j = relu(a_j*x + c_j); b1 cancels exactly in BN.
    float g1v = g1[l*H_ + j];
    float w1 = (v1[l*H_ + j] >= 0.f) ? g1v : -g1v;
    double rr = 1.0 / sqrt(vx * (double)g1v * g1v + 1e-5);
    float a = (float)((double)w1 * rr * bn1g[l*H_ + j]);
    float c = (float)((double)bn1b[l*H_ + j] - mx * a);
    float tj = (a != 0.f) ? (float)(-(double)c / a) : INFINITY;
    sA[j] = a; sC[j] = c; sT[j] = tj;
    __syncthreads();

    int rk = 0;
    for (int q = 0; q < H_; q++) {
        float tq = sT[q];
        rk += ((tq < tj) || (tq == tj && q < j)) ? 1 : 0;
    }
    order[rk] = j;

    float vv = v2[l*H_*H_ + i*H_ + j];
    vrow[j] = vv;
    double n2 = bredd((double)vv * vv, redd, j);   // syncs order/vrow too
    double wsc = (double)g2[l*H_ + i] / sqrt(n2);
    double w = wsc * vv;
    bool bm = (a < 0.f) || (a == 0.f && c > 0.f);  // active at x=-inf
    double base1 = bredd(bm ? w * a : 0.0, redd, j);
    double base0 = bredd(bm ? w * c : 0.0, redd, j);

    // delta for interval step k = j+1: toggle unit order[j]
    int jj = order[j];
    float aa = sA[jj], cc = sC[jj], vj = vrow[jj];
    double d1 = 0.0, d0 = 0.0;
    if (aa != 0.f) {
        double sg = (aa > 0.f) ? 1.0 : -1.0;
        double wj = wsc * vj;
        d1 = sg * wj * aa; d0 = sg * wj * cc;
    }
    scan2[j] = make_double2(d1, d0);
    __syncthreads();
    for (int off = 1; off < H_; off <<= 1) {
        double2 add = (j >= off) ? scan2[j - off] : make_double2(0.0, 0.0);
        __syncthreads();
        scan2[j].x += add.x; scan2[j].y += add.y;
        __syncthreads();
    }
    double b2i = b2[l*H_ + i];
    float2* S = (float2*)(ws + OFF_S);
    double2 sj = scan2[j];
    S[(j + 1)*H_ + i] = make_float2((float)(base1 + sj.x), (float)(base0 + sj.y + b2i));
    if (j == 0) S[i] = make_float2((float)base1, (float)(base0 + b2i));

    if (i == 0) {
        ws[OFF_TS + rk] = tj;                      // sorted ascending
        float* bins = ws + OFF_BIN;
        bins[j] = 0.f; bins[j + 128] = 0.f; bins[j + 256] = 0.f; bins[j + 384] = 0.f;
        if (j < 2) ws[OFF_ST + 2*(1 - par) + j] = 0.f;
    }
}

// 256 x 1024: lower_bound bin + per-interval (cnt, sum x, sum x^2)
__global__ __launch_bounds__(1024) void k_hist(float* __restrict__ ws, int rev) {
    const int tid = threadIdx.x;
    const int b = blockIdx.x * 1024 + tid;
    __shared__ float lts[H_];
    __shared__ float lb[4 * 396];
    if (tid < H_) lts[tid] = ws[OFF_TS + tid];
    for (int e = tid; e < 4 * 396; e += 1024) lb[e] = 0.f;
    __syncthreads();
    float x = rev ? ws[BN_ + b] : ws[b];
    int lo = 0, hi = 128;
    while (lo < hi) {                    // lower_bound: bin = #{t < x}
        int mid = (lo + hi) >> 1;        // mid <= 127, always in bounds
        if (lts[mid] < x) lo = mid + 1; else hi = mid;
    }
    int bin = lo;
    ((unsigned char*)(ws + OFF_BB))[b] = (unsigned char)bin;
    float* lbr = lb + ((tid >> 6) & 3) * 396;
    atomicAdd(&lbr[bin], 1.f);
    atomicAdd(&lbr[132 + bin], x);
    atomicAdd(&lbr[264 + bin], x * x);
    __syncthreads();
    float* bins = ws + OFF_BIN;
    for (int e = tid; e < 396; e += 1024) {
        float v = lb[e] + lb[396 + e] + lb[792 + e] + lb[1188 + e];
        atomicAdd(&bins[e], v);
    }
}

// 129 blocks x 128: exact BN2 stats per unit (interval moments, double),
// fold, find relu crossings inside interval k, sort, point-slope segments.
__global__ __launch_bounds__(128) void k_fin(
    const float* __restrict__ bn2g, const float* __restrict__ bn2b,
    const float* __restrict__ wf, const float* __restrict__ bf,
    float* __restrict__ ws, int l) {
    const int i = threadIdx.x, k = blockIdx.x;
    __shared__ double redd[2];
    __shared__ float xcS[H_], xsS[H_];
    __shared__ double2 dS[H_];
    const float2* S = (const float2*)(ws + OFF_S);
    const float* bins = ws + OFF_BIN;
    const float* ts = ws + OFF_TS;

    double M = 0.0, E = 0.0;
    for (int kk = 0; kk < NBINS; ++kk) {
        float2 s = S[kk*H_ + i];
        double cn = bins[kk], sx = bins[132 + kk], sxx = bins[264 + kk];
        M += (double)s.x * sx + (double)s.y * cn;
        E += (double)s.x * ((double)s.x * sxx + 2.0 * s.y * sx) + (double)s.y * s.y * cn;
    }
    double mean = M * (1.0 / BN_);
    double var = fmax(E * (1.0 / BN_) - mean * mean, 0.0);
    double R = (double)bn2g[l*H_ + i] / sqrt(var + 1e-5);
    float2 sk = S[k*H_ + i];
    float F1 = (float)((double)sk.x * R);
    float F0 = (float)(((double)sk.y - mean) * R + bn2b[l*H_ + i]);

    float lo = (k == 0) ? -3.0e38f : ts[k - 1];
    float hi = (k == NBINS - 1) ? 3.0e38f : ts[k];
    double hlo = (double)F1 * lo + F0;
    bool act = (k == 0) ? ((F1 < 0.f) || (F1 == 0.f && F0 > 0.f))
                        : ((hlo > 0.0) || (hlo == 0.0 && F1 > 0.f));
    bool has = false; float xc = INFINITY;
    if (F1 != 0.f) {
        double td = -(double)F0 / F1;
        if (td > lo && td < hi) { has = true; xc = (float)td; }
    }

    xcS[i] = xc;
    __syncthreads();
    int r = 0;
    for (int q = 0; q < H_; ++q) {
        float key = xcS[q];
        r += ((key < xc) || (key == xc && q < i)) ? 1 : 0;
    }
    double cntd = bredd(has ? 1.0 : 0.0, redd, i);
    int cnt = (int)(cntd + 0.5);
    float wfs = wf[l*2*H_ + i], wft = wf[l*2*H_ + H_ + i];
    if (has) {
        double sg = (F1 > 0.f) ? 1.0 : -1.0;
        dS[r] = make_double2(sg * (double)wfs * F1, sg * (double)wft * F1);
        xsS[r] = xc;
        ws[OFF_XS + k*132 + r] = xc;
    }
    __syncthreads();

    // ref0 inside segment 0's closure; V0 = direct relu-sum there (exact).
    float ref0 = (k == 0) ? ((cnt > 0) ? xsS[0] : ts[0]) : ts[k - 1];
    float hr = fmaxf(fmaf(F1, ref0, F0), 0.f);
    double Vs0 = bredd((double)wfs * hr, redd, i);
    double Vt0 = bredd((double)wft * hr, redd, i);
    double As0 = bredd(act ? (double)wfs * F1 : 0.0, redd, i);
    double At0 = bredd(act ? (double)wft * F1 : 0.0, redd, i);

    if (i == 0) {
        float4* seg = (float4*)ws + (OFF_SEG / 4) + k * 132;
        float* refk = ws + OFF_REF + k * 132;
        double As = As0, At = At0;
        double Vs = Vs0 + bf[2*l], Vt = Vt0 + bf[2*l + 1];
        float ref = ref0;
        seg[0] = make_float4((float)As, (float)Vs, (float)At, (float)Vt);
        refk[0] = ref;
        for (int r2 = 0; r2 < cnt; ++r2) {
            float xr = xsS[r2];
            Vs += As * (double)(xr - ref);
            Vt += At * (double)(xr - ref);
            As += dS[r2].x; At += dS[r2].y;
            ref = xr;
            seg[r2 + 1] = make_float4((float)As, (float)Vs, (float)At, (float)Vt);
            refk[r2 + 1] = ref;
        }
        ((int*)ws)[OFF_CNT + k] = cnt;
    }
}

// 256 x 1024: per-sample: segment lookup + point-slope eval + coupling.
__global__ __launch_bounds__(1024) void k_apply(
    float* __restrict__ ws, float* __restrict__ out,
    int l, int rev, int last, int par) {
    __shared__ float rsc[32];
    const int tid = threadIdx.x;
    const int b = blockIdx.x * 1024 + tid;
    float x0v = ws[b], x1v = ws[BN_ + b];
    float sl0 = ws[2*BN_ + b];
    int kb = ((const unsigned char*)(ws + OFF_BB))[b];
    float xin = rev ? x1v : x0v;
    float xo  = rev ? x0v : x1v;

    int cnt = ((const int*)ws)[OFF_CNT + kb];
    const float* xsk = ws + OFF_XS + kb * 132;
    int r = 0;
    while (r < cnt && xin > xsk[r]) ++r;
    float4 rec = ((const float4*)ws)[(OFF_SEG / 4) + kb * 132 + r];
    float ref = ws[OFF_REF + kb * 132 + r];
    float dx = xin - ref;
    float st_s = fmaf(rec.x, dx, rec.y);
    float st_t = fmaf(rec.z, dx, rec.w);
    float s = tanhf(st_s);
    float y = expf(s) * xo + st_t;
    float sl = sl0 + s;

    if (!last) {
        if (rev) ws[b] = y; else ws[BN_ + b] = y;
        ws[2*BN_ + b] = sl;
        float s1 = y, s2 = y * y;
        for (int off = 32; off; off >>= 1) {
            s1 += __shfl_down(s1, off);
            s2 += __shfl_down(s2, off);
        }
        int lane = tid & 63, wid = tid >> 6;
        if (lane == 0) { rsc[wid] = s1; rsc[16 + wid] = s2; }
        __syncthreads();
        if (tid == 0) {
            float a = 0.f, c = 0.f;
            for (int w = 0; w < 16; w++) { a += rsc[w]; c += rsc[16 + w]; }
            atomicAdd(&ws[OFF_ST + 2*(1 - par)], a);
            atomicAdd(&ws[OFF_ST + 2*(1 - par) + 1], c);
        }
    } else {
        float z0 = 1.f / (1.f + expf(-x0v));
        float z1 = 1.f / (1.f + expf(-y));
        ((float2*)out)[b] = make_float2(z0, z1);
        out[2*BN_ + b] = sl + logf(z0 * (1.f - z0) + 1e-4f)
                            + logf(z1 * (1.f - z1) + 1e-4f);
    }
}

extern "C" void kernel_launch(void* const* d_in, const int* in_sizes, int n_in,
                              void* d_out, int out_size, void* d_ws, size_t ws_size,
                              hipStream_t stream) {
    const float* x    = (const float*)d_in[0];
    const float* v1   = (const float*)d_in[1];
    const float* g1   = (const float*)d_in[2];
    // d_in[3] = b1: cancels exactly inside BN1, unused.
    const float* bn1g = (const float*)d_in[4];
    const float* bn1b = (const float*)d_in[5];
    const float* v2   = (const float*)d_in[6];
    const float* g2   = (const float*)d_in[7];
    const float* b2   = (const float*)d_in[8];
    const float* bn2g = (const float*)d_in[9];
    const float* bn2b = (const float*)d_in[10];
    const float* wf   = (const float*)d_in[11];
    const float* bf   = (const float*)d_in[12];
    float* ws  = (float*)d_ws;
    float* out = (float*)d_out;

    k_zero<<<1, 64, 0, stream>>>(ws);
    k_init<<<BN_/1024, 1024, 0, stream>>>(x, ws);
    for (int l = 0; l < 8; l++) {
        int rev = (l % 2 == 0) ? 1 : 0;
        int par = l & 1;
        int last = (l == 7) ? 1 : 0;
        k_prep<<<128, 128, 0, stream>>>(v1, g1, bn1g, bn1b, v2, g2, b2, ws, l, par);
        k_hist<<<BN_/1024, 1024, 0, stream>>>(ws, rev);
        k_fin<<<NBINS, 128, 0, stream>>>(bn2g, bn2b, wf, bf, ws, l);
        k_apply<<<BN_/1024, 1024, 0, stream>>>(ws, out, l, rev, last, par);
    }
}